// Round 2
// baseline (4503.960 us; speedup 1.0000x reference)
//
#include <hip/hip_runtime.h>

// Problem constants
#define N_VEC 32768   // B*H*W
#define K_CB  8192
#define C_DIM 256
#define B_DIM 32
#define HW    1024

// out layout (floats)
#define OFF_Q     0                      // 8388608
#define OFF_IDX   8388608                // 32768
#define OFF_VQ    8421376                // 1
#define OFF_PERP  8421377                // 1
#define OFF_ACT   8421378                // 1
#define OFF_USAGE 8421379                // 8192
#define OFF_EMBED 8429571                // 2097152
// total 10526723

// ws layout (bytes)
#define WS_CBT    0                      // 256*8192*4 = 8388608
#define WS_CN     8388608                // 8192*4 = 32768
#define WS_PACKED 8421376                // 32768*8 = 262144

// ---------------- codebook transpose: cb[K][C] -> cbt[C][K] ----------------
__global__ void transpose_cb(const float* __restrict__ cb, float* __restrict__ cbt) {
    __shared__ float t[32][33];
    int k0 = blockIdx.x * 32, c0 = blockIdx.y * 32;
    int tx = threadIdx.x, ty = threadIdx.y;   // (32, 8)
    #pragma unroll
    for (int i = 0; i < 32; i += 8)
        t[ty + i][tx] = cb[(size_t)(k0 + ty + i) * C_DIM + c0 + tx];
    __syncthreads();
    #pragma unroll
    for (int i = 0; i < 32; i += 8)
        cbt[(size_t)(c0 + ty + i) * K_CB + k0 + tx] = t[tx][ty + i];
}

// ---------------- codebook norms ----------------
__global__ void cnorm_k(const float4* __restrict__ cb4, float* __restrict__ cn) {
    int k = blockIdx.x;
    int l = threadIdx.x;                      // 64 lanes = 1 wave
    float4 v = cb4[(size_t)k * 64 + l];
    float s = v.x * v.x + v.y * v.y + v.z * v.z + v.w * v.w;
    #pragma unroll
    for (int off = 32; off; off >>= 1) s += __shfl_down(s, off, 64);
    if (l == 0) cn[k] = s;
}

// ---------------- fused GEMM + argmin ----------------
// grid (256 n-blocks, 4 k-splits), block 256 (16 tx x 16 ty), thread tile 8n x 8k
#define BM 128
#define BN 128
#define BC 16
#define KSPLIT 2048   // K per k-split
#define KTILES 16     // KSPLIT / BN

__launch_bounds__(256, 4)
__global__ void gemm_argmin(const float* __restrict__ z, const float* __restrict__ cbt,
                            const float* __restrict__ cn,
                            unsigned long long* __restrict__ packed) {
    __shared__ float vs[BC][BM];
    __shared__ float cs[BC][BN];
    __shared__ float cns[BN];
    __shared__ float rv[BM][16];
    __shared__ int   ri[BM][16];

    int nb = blockIdx.x;
    int ks = blockIdx.y;
    int n0 = nb * BM;
    int b  = n0 >> 10;          // BM=128 divides HW=1024 -> same b for whole block
    int hw0 = n0 & 1023;
    int t = threadIdx.x;
    int tx = t & 15, ty = t >> 4;

    float minv[8];
    int   mini[8];
    #pragma unroll
    for (int i = 0; i < 8; i++) { minv[i] = 3.4e38f; mini[i] = 0; }

    for (int kt = 0; kt < KTILES; kt++) {
        int kbase = ks * KSPLIT + kt * BN;
        float acc[8][8];
        #pragma unroll
        for (int i = 0; i < 8; i++)
            #pragma unroll
            for (int j = 0; j < 8; j++) acc[i][j] = 0.f;

        for (int c0 = 0; c0 < C_DIM; c0 += BC) {
            __syncthreads();
            // stage v chunk directly from z: vs[cc][nl] = z[b][c0+cc][hw0+nl]
            #pragma unroll
            for (int r = 0; r < 2; r++) {
                int ff = t + r * 256;           // 512 float4 total
                int cc = ff >> 5, col = ff & 31;
                float4 x = *(const float4*)(z + (((size_t)(b * C_DIM + c0 + cc)) << 10) + hw0 + col * 4);
                *(float4*)(&vs[cc][col * 4]) = x;
            }
            // stage cbt chunk: cs[cc][kl] = cbt[c0+cc][kbase+kl]
            #pragma unroll
            for (int r = 0; r < 2; r++) {
                int ff = t + r * 256;
                int cc = ff >> 5, col = ff & 31;
                float4 x = *(const float4*)(cbt + (size_t)(c0 + cc) * K_CB + kbase + col * 4);
                *(float4*)(&cs[cc][col * 4]) = x;
            }
            if (c0 == 0 && t < 32) {
                float4 x = *(const float4*)(cn + kbase + t * 4);
                *(float4*)(&cns[t * 4]) = x;
            }
            __syncthreads();

            #pragma unroll
            for (int cc = 0; cc < BC; cc++) {
                float a[8], bb[8];
                *(float4*)(a)      = *(const float4*)(&vs[cc][ty * 8]);
                *(float4*)(a + 4)  = *(const float4*)(&vs[cc][ty * 8 + 4]);
                *(float4*)(bb)     = *(const float4*)(&cs[cc][tx * 8]);
                *(float4*)(bb + 4) = *(const float4*)(&cs[cc][tx * 8 + 4]);
                #pragma unroll
                for (int i = 0; i < 8; i++)
                    #pragma unroll
                    for (int j = 0; j < 8; j++)
                        acc[i][j] += a[i] * bb[j];
            }
        }
        // score = ||c||^2 - 2 v.c ; running argmin (ascending k order -> first-min tie-break)
        #pragma unroll
        for (int i = 0; i < 8; i++) {
            #pragma unroll
            for (int j = 0; j < 8; j++) {
                int kl = tx * 8 + j;
                float s = cns[kl] - 2.0f * acc[i][j];
                if (s < minv[i]) { minv[i] = s; mini[i] = kbase + kl; }
            }
        }
    }

    __syncthreads();
    #pragma unroll
    for (int i = 0; i < 8; i++) { rv[ty * 8 + i][tx] = minv[i]; ri[ty * 8 + i][tx] = mini[i]; }
    __syncthreads();
    if (t < BM) {
        float bv = rv[t][0]; int bi = ri[t][0];
        #pragma unroll
        for (int x = 1; x < 16; x++) {
            float v = rv[t][x]; int ii = ri[t][x];
            if (v < bv || (v == bv && ii < bi)) { bv = v; bi = ii; }
        }
        unsigned u = __float_as_uint(bv);
        u = (u & 0x80000000u) ? ~u : (u | 0x80000000u);
        unsigned long long key = ((unsigned long long)u << 32) | (unsigned)bi;
        atomicMin(&packed[n0 + t], key);
    }
}

// ---------------- gather + losses + histograms ----------------
// grid 512 (64 n each), block 256: lane = n, grp = c-quarter
__global__ void gather_k(const float* __restrict__ z, const float* __restrict__ cb,
                         const unsigned long long* __restrict__ packed,
                         float* __restrict__ out_q, float* __restrict__ out_idx,
                         float* __restrict__ out_vq, float* __restrict__ usage,
                         float* __restrict__ embed) {
    int t = threadIdx.x;
    int lane = t & 63, grp = t >> 6;
    int n = blockIdx.x * 64 + lane;
    int idx = (int)(unsigned)(packed[n] & 0xffffffffULL);
    int b = n >> 10, hw = n & 1023;
    if (grp == 0) {
        out_idx[n] = (float)idx;
        atomicAdd(usage + idx, 1.0f);
    }
    const float* cbrow = cb + (size_t)idx * C_DIM;
    float local = 0.f;
    for (int cc = 0; cc < 64; cc++) {
        int c = grp * 64 + cc;
        size_t zoff = (((size_t)(b * C_DIM + c)) << 10) + hw;
        float zv = z[zoff];
        float q  = cbrow[c];
        out_q[zoff] = q;
        float d = q - zv;
        local += d * d;
        atomicAdd(embed + (size_t)idx * C_DIM + c, zv);
    }
    #pragma unroll
    for (int off = 32; off; off >>= 1) local += __shfl_down(local, off, 64);
    __shared__ float part[4];
    if (lane == 0) part[grp] = local;
    __syncthreads();
    if (t == 0) {
        float s = part[0] + part[1] + part[2] + part[3];
        atomicAdd(out_vq, s * (1.0f / 8388608.0f));
    }
}

// ---------------- perplexity / active codes ----------------
__global__ void metrics_k(const float* __restrict__ usage, float* __restrict__ perp,
                          float* __restrict__ act) {
    __shared__ float sh[256];
    int t = threadIdx.x;
    float s = 0.f;
    for (int i = t; i < K_CB; i += 256) s += usage[i];
    sh[t] = s; __syncthreads();
    for (int off = 128; off; off >>= 1) { if (t < off) sh[t] += sh[t + off]; __syncthreads(); }
    float S = sh[0] > 1.0f ? sh[0] : 1.0f;
    __syncthreads();
    float pl = 0.f, a = 0.f;
    for (int i = t; i < K_CB; i += 256) {
        float u = usage[i];
        float p = u / S;
        float pm = p > 1e-10f ? p : 1e-10f;
        pl += p * logf(pm);
        a += (u > 0.f) ? 1.f : 0.f;
    }
    sh[t] = pl; __syncthreads();
    for (int off = 128; off; off >>= 1) { if (t < off) sh[t] += sh[t + off]; __syncthreads(); }
    if (t == 0) *perp = expf(-sh[0]);
    __syncthreads();
    sh[t] = a; __syncthreads();
    for (int off = 128; off; off >>= 1) { if (t < off) sh[t] += sh[t + off]; __syncthreads(); }
    if (t == 0) *act = sh[0];
}

extern "C" void kernel_launch(void* const* d_in, const int* in_sizes, int n_in,
                              void* d_out, int out_size, void* d_ws, size_t ws_size,
                              hipStream_t stream) {
    const float* z  = (const float*)d_in[0];
    const float* cb = (const float*)d_in[1];
    float* out = (float*)d_out;
    char* ws = (char*)d_ws;

    float* cbt = (float*)(ws + WS_CBT);
    float* cn  = (float*)(ws + WS_CN);
    unsigned long long* packed = (unsigned long long*)(ws + WS_PACKED);

    float* out_q     = out + OFF_Q;
    float* out_idx   = out + OFF_IDX;
    float* out_vq    = out + OFF_VQ;
    float* out_perp  = out + OFF_PERP;
    float* out_act   = out + OFF_ACT;
    float* out_usage = out + OFF_USAGE;
    float* out_embed = out + OFF_EMBED;

    // zero accumulators (vq, perp, act, usage, embed are contiguous) and init packed keys
    hipMemsetAsync(out_vq, 0, (size_t)(1 + 1 + 1 + K_CB + K_CB * C_DIM) * sizeof(float), stream);
    hipMemsetAsync(packed, 0xFF, (size_t)N_VEC * 8, stream);

    transpose_cb<<<dim3(K_CB / 32, C_DIM / 32), dim3(32, 8), 0, stream>>>(cb, cbt);
    cnorm_k<<<K_CB, 64, 0, stream>>>((const float4*)cb, cn);
    gemm_argmin<<<dim3(N_VEC / BM, K_CB / KSPLIT), 256, 0, stream>>>(z, cbt, cn, packed);
    gather_k<<<N_VEC / 64, 256, 0, stream>>>(z, cb, packed, out_q, out_idx, out_vq,
                                             out_usage, out_embed);
    metrics_k<<<1, 256, 0, stream>>>(out_usage, out_perp, out_act);
}

// Round 10
// 2335.584 us; speedup vs baseline: 1.9284x; 1.9284x over previous
//
#include <hip/hip_runtime.h>

// Problem constants
#define N_VEC 32768   // B*H*W
#define K_CB  8192
#define C_DIM 256
#define B_DIM 32
#define HW    1024

// out layout (floats)
#define OFF_Q     0                      // 8388608
#define OFF_IDX   8388608                // 32768
#define OFF_VQ    8421376                // 1
#define OFF_PERP  8421377                // 1
#define OFF_ACT   8421378                // 1
#define OFF_USAGE 8421379                // 8192
#define OFF_EMBED 8429571                // 2097152

// ws layout (bytes)
#define WS_CBT    0                      // 256*8192*4 = 8388608
#define WS_CN     8388608                // 8192*4 = 32768
#define WS_PACKED 8421376                // 32768*8 = 262144

// ---------------- codebook transpose: cb[K][C] -> cbt[C][K] ----------------
__global__ void transpose_cb(const float* __restrict__ cb, float* __restrict__ cbt) {
    __shared__ float t[32][33];
    int k0 = blockIdx.x * 32, c0 = blockIdx.y * 32;
    int tx = threadIdx.x, ty = threadIdx.y;   // (32, 8)
    #pragma unroll
    for (int i = 0; i < 32; i += 8)
        t[ty + i][tx] = cb[(size_t)(k0 + ty + i) * C_DIM + c0 + tx];
    __syncthreads();
    #pragma unroll
    for (int i = 0; i < 32; i += 8)
        cbt[(size_t)(c0 + ty + i) * K_CB + k0 + tx] = t[tx][ty + i];
}

// ---------------- codebook norms ----------------
__global__ void cnorm_k(const float4* __restrict__ cb4, float* __restrict__ cn) {
    int k = blockIdx.x;
    int l = threadIdx.x;                      // 64 lanes = 1 wave
    float4 v = cb4[(size_t)k * 64 + l];
    float s = v.x * v.x + v.y * v.y + v.z * v.z + v.w * v.w;
    #pragma unroll
    for (int off = 32; off; off >>= 1) s += __shfl_down(s, off, 64);
    if (l == 0) cn[k] = s;
}

// ---------------- fused GEMM + argmin ----------------
// grid (256 n-blocks, 4 k-splits), block 256 (16 tx x 16 ty), thread tile 8n x 8k
#define BM 128
#define BN 128
#define BC 16
#define KSPLIT 2048   // K per k-split
#define KTILES 16     // KSPLIT / BN

__launch_bounds__(256, 2)
__global__ void gemm_argmin(const float* __restrict__ z, const float* __restrict__ cbt,
                            const float* __restrict__ cn,
                            unsigned long long* __restrict__ packed) {
    __shared__ float vs[BC][BM];
    __shared__ float cs[BC][BN];
    __shared__ float cns[BN];
    __shared__ float rv[BM][16];
    __shared__ int   ri[BM][16];

    int nb = blockIdx.x;
    int ks = blockIdx.y;
    int n0 = nb * BM;
    int b  = n0 >> 10;          // BM=128 divides HW=1024 -> same b for whole block
    int hw0 = n0 & 1023;
    int t = threadIdx.x;
    int tx = t & 15, ty = t >> 4;

    float minv[8];
    int   mini[8];
    #pragma unroll
    for (int i = 0; i < 8; i++) { minv[i] = 3.4e38f; mini[i] = 0; }

    for (int kt = 0; kt < KTILES; kt++) {
        int kbase = ks * KSPLIT + kt * BN;
        float acc[8][8];
        #pragma unroll
        for (int i = 0; i < 8; i++)
            #pragma unroll
            for (int j = 0; j < 8; j++) acc[i][j] = 0.f;

        for (int c0 = 0; c0 < C_DIM; c0 += BC) {
            __syncthreads();
            // stage v chunk directly from z: vs[cc][nl] = z[b][c0+cc][hw0+nl]
            #pragma unroll
            for (int r = 0; r < 2; r++) {
                int ff = t + r * 256;           // 512 float4 total
                int cc = ff >> 5, col = ff & 31;
                float4 x = *(const float4*)(z + (((size_t)(b * C_DIM + c0 + cc)) << 10) + hw0 + col * 4);
                *(float4*)(&vs[cc][col * 4]) = x;
            }
            // stage cbt chunk: cs[cc][kl] = cbt[c0+cc][kbase+kl]
            #pragma unroll
            for (int r = 0; r < 2; r++) {
                int ff = t + r * 256;
                int cc = ff >> 5, col = ff & 31;
                float4 x = *(const float4*)(cbt + (size_t)(c0 + cc) * K_CB + kbase + col * 4);
                *(float4*)(&cs[cc][col * 4]) = x;
            }
            if (c0 == 0 && t < 32) {
                float4 x = *(const float4*)(cn + kbase + t * 4);
                *(float4*)(&cns[t * 4]) = x;
            }
            __syncthreads();

            #pragma unroll
            for (int cc = 0; cc < BC; cc++) {
                const float4 a0 = *(const float4*)(&vs[cc][ty * 8]);
                const float4 a1 = *(const float4*)(&vs[cc][ty * 8 + 4]);
                const float4 b0 = *(const float4*)(&cs[cc][tx * 8]);
                const float4 b1 = *(const float4*)(&cs[cc][tx * 8 + 4]);
#define VQ_ROW(I, AV) \
                acc[I][0] += (AV) * b0.x; acc[I][1] += (AV) * b0.y; \
                acc[I][2] += (AV) * b0.z; acc[I][3] += (AV) * b0.w; \
                acc[I][4] += (AV) * b1.x; acc[I][5] += (AV) * b1.y; \
                acc[I][6] += (AV) * b1.z; acc[I][7] += (AV) * b1.w;
                VQ_ROW(0, a0.x) VQ_ROW(1, a0.y) VQ_ROW(2, a0.z) VQ_ROW(3, a0.w)
                VQ_ROW(4, a1.x) VQ_ROW(5, a1.y) VQ_ROW(6, a1.z) VQ_ROW(7, a1.w)
#undef VQ_ROW
            }
        }
        // score = ||c||^2 - 2 v.c ; running argmin (ascending k order -> first-min tie-break)
        #pragma unroll
        for (int i = 0; i < 8; i++) {
            #pragma unroll
            for (int j = 0; j < 8; j++) {
                int kl = tx * 8 + j;
                float s = cns[kl] - 2.0f * acc[i][j];
                if (s < minv[i]) { minv[i] = s; mini[i] = kbase + kl; }
            }
        }
    }

    __syncthreads();
    #pragma unroll
    for (int i = 0; i < 8; i++) { rv[ty * 8 + i][tx] = minv[i]; ri[ty * 8 + i][tx] = mini[i]; }
    __syncthreads();
    if (t < BM) {
        float bv = rv[t][0]; int bi = ri[t][0];
        #pragma unroll
        for (int x = 1; x < 16; x++) {
            float v = rv[t][x]; int ii = ri[t][x];
            if (v < bv || (v == bv && ii < bi)) { bv = v; bi = ii; }
        }
        unsigned u = __float_as_uint(bv);
        u = (u & 0x80000000u) ? ~u : (u | 0x80000000u);
        unsigned long long key = ((unsigned long long)u << 32) | (unsigned)bi;
        atomicMin(&packed[n0 + t], key);
    }
}

// ---------------- gather + losses + histograms ----------------
// grid 512 (64 n each), block 256: lane = n, grp = c-quarter
__global__ void gather_k(const float* __restrict__ z, const float* __restrict__ cb,
                         const unsigned long long* __restrict__ packed,
                         float* __restrict__ out_q, float* __restrict__ out_idx,
                         float* __restrict__ out_vq, float* __restrict__ usage,
                         float* __restrict__ embed) {
    int t = threadIdx.x;
    int lane = t & 63, grp = t >> 6;
    int n = blockIdx.x * 64 + lane;
    int idx = (int)(unsigned)(packed[n] & 0xffffffffULL);
    int b = n >> 10, hw = n & 1023;
    if (grp == 0) {
        out_idx[n] = (float)idx;
        atomicAdd(usage + idx, 1.0f);
    }
    const float* cbrow = cb + (size_t)idx * C_DIM;
    float local = 0.f;
    for (int cc = 0; cc < 64; cc++) {
        int c = grp * 64 + cc;
        size_t zoff = (((size_t)(b * C_DIM + c)) << 10) + hw;
        float zv = z[zoff];
        float q  = cbrow[c];
        out_q[zoff] = q;
        float d = q - zv;
        local += d * d;
        atomicAdd(embed + (size_t)idx * C_DIM + c, zv);
    }
    #pragma unroll
    for (int off = 32; off; off >>= 1) local += __shfl_down(local, off, 64);
    __shared__ float part[4];
    if (lane == 0) part[grp] = local;
    __syncthreads();
    if (t == 0) {
        float s = part[0] + part[1] + part[2] + part[3];
        atomicAdd(out_vq, s * (1.0f / 8388608.0f));
    }
}

// ---------------- perplexity / active codes ----------------
__global__ void metrics_k(const float* __restrict__ usage, float* __restrict__ perp,
                          float* __restrict__ act) {
    __shared__ float sh[256];
    int t = threadIdx.x;
    float s = 0.f;
    for (int i = t; i < K_CB; i += 256) s += usage[i];
    sh[t] = s; __syncthreads();
    for (int off = 128; off; off >>= 1) { if (t < off) sh[t] += sh[t + off]; __syncthreads(); }
    float S = sh[0] > 1.0f ? sh[0] : 1.0f;
    __syncthreads();
    float pl = 0.f, a = 0.f;
    for (int i = t; i < K_CB; i += 256) {
        float u = usage[i];
        float p = u / S;
        float pm = p > 1e-10f ? p : 1e-10f;
        pl += p * logf(pm);
        a += (u > 0.f) ? 1.f : 0.f;
    }
    sh[t] = pl; __syncthreads();
    for (int off = 128; off; off >>= 1) { if (t < off) sh[t] += sh[t + off]; __syncthreads(); }
    if (t == 0) *perp = expf(-sh[0]);
    __syncthreads();
    sh[t] = a; __syncthreads();
    for (int off = 128; off; off >>= 1) { if (t < off) sh[t] += sh[t + off]; __syncthreads(); }
    if (t == 0) *act = sh[0];
}

extern "C" void kernel_launch(void* const* d_in, const int* in_sizes, int n_in,
                              void* d_out, int out_size, void* d_ws, size_t ws_size,
                              hipStream_t stream) {
    const float* z  = (const float*)d_in[0];
    const float* cb = (const float*)d_in[1];
    float* out = (float*)d_out;
    char* ws = (char*)d_ws;

    float* cbt = (float*)(ws + WS_CBT);
    float* cn  = (float*)(ws + WS_CN);
    unsigned long long* packed = (unsigned long long*)(ws + WS_PACKED);

    float* out_q     = out + OFF_Q;
    float* out_idx   = out + OFF_IDX;
    float* out_vq    = out + OFF_VQ;
    float* out_perp  = out + OFF_PERP;
    float* out_act   = out + OFF_ACT;
    float* out_usage = out + OFF_USAGE;
    float* out_embed = out + OFF_EMBED;

    // zero accumulators (vq, perp, act, usage, embed are contiguous) and init packed keys
    hipMemsetAsync(out_vq, 0, (size_t)(1 + 1 + 1 + K_CB + K_CB * C_DIM) * sizeof(float), stream);
    hipMemsetAsync(packed, 0xFF, (size_t)N_VEC * 8, stream);

    transpose_cb<<<dim3(K_CB / 32, C_DIM / 32), dim3(32, 8), 0, stream>>>(cb, cbt);
    cnorm_k<<<K_CB, 64, 0, stream>>>((const float4*)cb, cn);
    gemm_argmin<<<dim3(N_VEC / BM, K_CB / KSPLIT), 256, 0, stream>>>(z, cbt, cn, packed);
    gather_k<<<N_VEC / 64, 256, 0, stream>>>(z, cb, packed, out_q, out_idx, out_vq,
                                             out_usage, out_embed);
    metrics_k<<<1, 256, 0, stream>>>(out_usage, out_perp, out_act);
}

// Round 12
// 979.827 us; speedup vs baseline: 4.5967x; 2.3837x over previous
//
#include <hip/hip_runtime.h>

// Problem constants
#define N_VEC 32768   // B*H*W
#define K_CB  8192
#define C_DIM 256

// out layout (floats)
#define OFF_Q     0                      // 8388608
#define OFF_IDX   8388608                // 32768
#define OFF_VQ    8421376                // 1
#define OFF_PERP  8421377                // 1
#define OFF_ACT   8421378                // 1
#define OFF_USAGE 8421379                // 8192
#define OFF_EMBED 8429571                // 2097152

// ws layout (bytes) -- total 8.68 MB (same footprint as proven round-2 kernel)
#define WS_CBH    0                      // 8192*256*2 = 4194304
#define WS_CBL    4194304                // 4194304
#define WS_CN     8388608                // 8192*4 = 32768
#define WS_PACKED 8421376                // 32768*8 = 262144

typedef unsigned long long u64;
typedef unsigned short u16;
typedef unsigned int u32;
typedef float f32x4 __attribute__((ext_vector_type(4)));
typedef short s16x8 __attribute__((ext_vector_type(8)));

__device__ __forceinline__ u16 rne_bf16(float x) {
    u32 u = __float_as_uint(x);
    return (u16)((u + 0x7fffu + ((u >> 16) & 1u)) >> 16);   // RNE; bf16 = top half of fp32
}
__device__ __forceinline__ float bf16f(u16 h) { return __uint_as_float(((u32)h) << 16); }

// ---------------- codebook split: cbh/cbl = bf16 split of (-2 * cb), [K][C] ----------------
__global__ void split_cb(const float* __restrict__ cb, u16* __restrict__ cbh,
                         u16* __restrict__ cbl) {
    int i = (blockIdx.x * 256 + threadIdx.x) * 4;
    float4 v = *(const float4*)(cb + i);
    ushort4 h, l;
    { float a = -2.0f * v.x; h.x = rne_bf16(a); l.x = rne_bf16(a - bf16f(h.x)); }
    { float a = -2.0f * v.y; h.y = rne_bf16(a); l.y = rne_bf16(a - bf16f(h.y)); }
    { float a = -2.0f * v.z; h.z = rne_bf16(a); l.z = rne_bf16(a - bf16f(h.z)); }
    { float a = -2.0f * v.w; h.w = rne_bf16(a); l.w = rne_bf16(a - bf16f(h.w)); }
    *(ushort4*)(cbh + i) = h;
    *(ushort4*)(cbl + i) = l;
}

// ---------------- codebook norms (fp32, unscaled cb) ----------------
__global__ void cnorm_k(const float4* __restrict__ cb4, float* __restrict__ cn) {
    int k = blockIdx.x;
    int l = threadIdx.x;                      // 64 lanes = 1 wave
    float4 v = cb4[(size_t)k * 64 + l];
    float s = v.x * v.x + v.y * v.y + v.z * v.z + v.w * v.w;
    #pragma unroll
    for (int off = 32; off; off >>= 1) s += __shfl_down(s, off, 64);
    if (l == 0) cn[k] = s;
}

// ---------------- z transpose + bf16 split: zh/zl [N][C] (stored in out_q scratch) ----------------
__global__ void split_z(const float* __restrict__ z, u16* __restrict__ zh,
                        u16* __restrict__ zl) {
    __shared__ float tile[32][33];
    int hw0 = blockIdx.x * 32, c0 = blockIdx.y * 32, b = blockIdx.z;
    int tx = threadIdx.x, ty = threadIdx.y;   // (32, 8)
    #pragma unroll
    for (int i = 0; i < 32; i += 8)
        tile[ty + i][tx] = z[(size_t)b * 262144 + (size_t)(c0 + ty + i) * 1024 + hw0 + tx];
    __syncthreads();
    #pragma unroll
    for (int i = 0; i < 32; i += 8) {
        float v = tile[tx][ty + i];           // (c = c0+tx, hw = hw0+ty+i)
        int n = b * 1024 + hw0 + ty + i;
        u16 h = rne_bf16(v);
        u16 lo = rne_bf16(v - bf16f(h));
        zh[(size_t)n * 256 + c0 + tx] = h;
        zl[(size_t)n * 256 + c0 + tx] = lo;
    }
}

// ---------------- MFMA GEMM + argmin ----------------
// grid (64 k-tiles, 256 n-tiles), block 256 = 4 waves (2k x 2n), wave tile 64k x 64n.
// score(k,n) = cn[k] + sum_c (-2c)[k][c] * v[n][c], 4 bf16 term-GEMMs into one fp32 acc.
__launch_bounds__(256, 2)
__global__ void gemm_mfma(const u16* __restrict__ cbh, const u16* __restrict__ cbl,
                          const u16* __restrict__ zh, const u16* __restrict__ zl,
                          const float* __restrict__ cn, u64* __restrict__ packed) {
    __shared__ __align__(16) u16 Ah[128 * 32], Al[128 * 32], Bh[128 * 32], Bl[128 * 32];
    const int kbase = blockIdx.x * 128, nbase = blockIdx.y * 128;
    const int t = threadIdx.x, lane = t & 63, w = t >> 6;
    const int wk = (w >> 1) * 64, wn = (w & 1) * 64;
    const int l15 = lane & 15, l4 = lane >> 4;

    f32x4 acc[4][4];
    const f32x4 zero4 = {0.f, 0.f, 0.f, 0.f};
    #pragma unroll
    for (int i = 0; i < 4; i++)
        #pragma unroll
        for (int j = 0; j < 4; j++) acc[i][j] = zero4;

    // staging chunk geometry: chunk f (0..511) = 16B: row f>>2, col8 (f&3)*8
    const int f0 = t, f1 = t + 256;
    const int ar0 = f0 >> 2, ac0 = (f0 & 3) * 8;
    const int ar1 = f1 >> 2, ac1 = (f1 & 3) * 8;
    const u16* gA0 = cbh + (size_t)(kbase + ar0) * 256 + ac0;
    const u16* gA1 = cbh + (size_t)(kbase + ar1) * 256 + ac1;
    const u16* gAl0 = cbl + (size_t)(kbase + ar0) * 256 + ac0;
    const u16* gAl1 = cbl + (size_t)(kbase + ar1) * 256 + ac1;
    const u16* gB0 = zh + (size_t)(nbase + ar0) * 256 + ac0;
    const u16* gB1 = zh + (size_t)(nbase + ar1) * 256 + ac1;
    const u16* gBl0 = zl + (size_t)(nbase + ar0) * 256 + ac0;
    const u16* gBl1 = zl + (size_t)(nbase + ar1) * 256 + ac1;

    // prologue loads (cs = 0)
    uint4 rA0 = *(const uint4*)(gA0);
    uint4 rA1 = *(const uint4*)(gA1);
    uint4 rAl0 = *(const uint4*)(gAl0);
    uint4 rAl1 = *(const uint4*)(gAl1);
    uint4 rB0 = *(const uint4*)(gB0);
    uint4 rB1 = *(const uint4*)(gB1);
    uint4 rBl0 = *(const uint4*)(gBl0);
    uint4 rBl1 = *(const uint4*)(gBl1);

    for (int cs = 0; cs < 8; ++cs) {
        __syncthreads();                       // all waves done reading previous LDS tile
        *(uint4*)(Ah + f0 * 8) = rA0;  *(uint4*)(Ah + f1 * 8) = rA1;
        *(uint4*)(Al + f0 * 8) = rAl0; *(uint4*)(Al + f1 * 8) = rAl1;
        *(uint4*)(Bh + f0 * 8) = rB0;  *(uint4*)(Bh + f1 * 8) = rB1;
        *(uint4*)(Bl + f0 * 8) = rBl0; *(uint4*)(Bl + f1 * 8) = rBl1;
        __syncthreads();

        // fragment loads: A rows wk+i*16+l15, B rows wn+j*16+l15, cols l4*8..+7
        s16x8 fah[4], fal[4], fbh[4], fbl[4];
        #pragma unroll
        for (int i = 0; i < 4; i++) {
            int ao = (wk + i * 16 + l15) * 32 + l4 * 8;
            int bo = (wn + i * 16 + l15) * 32 + l4 * 8;
            fah[i] = *(const s16x8*)(Ah + ao);
            fal[i] = *(const s16x8*)(Al + ao);
            fbh[i] = *(const s16x8*)(Bh + bo);
            fbl[i] = *(const s16x8*)(Bl + bo);
        }

        // prefetch next K-chunk while MFMAs run
        if (cs < 7) {
            int c0n = (cs + 1) * 32;
            rA0 = *(const uint4*)(gA0 + c0n);  rA1 = *(const uint4*)(gA1 + c0n);
            rAl0 = *(const uint4*)(gAl0 + c0n); rAl1 = *(const uint4*)(gAl1 + c0n);
            rB0 = *(const uint4*)(gB0 + c0n);  rB1 = *(const uint4*)(gB1 + c0n);
            rBl0 = *(const uint4*)(gBl0 + c0n); rBl1 = *(const uint4*)(gBl1 + c0n);
        }

        #pragma unroll
        for (int i = 0; i < 4; i++)
            #pragma unroll
            for (int j = 0; j < 4; j++) {
                acc[i][j] = __builtin_amdgcn_mfma_f32_16x16x32_bf16(fah[i], fbh[j], acc[i][j], 0, 0, 0);
                acc[i][j] = __builtin_amdgcn_mfma_f32_16x16x32_bf16(fah[i], fbl[j], acc[i][j], 0, 0, 0);
                acc[i][j] = __builtin_amdgcn_mfma_f32_16x16x32_bf16(fal[i], fbh[j], acc[i][j], 0, 0, 0);
                acc[i][j] = __builtin_amdgcn_mfma_f32_16x16x32_bf16(fal[i], fbl[j], acc[i][j], 0, 0, 0);
            }
    }

    // epilogue: D row (code) = (l>>4)*4 + reg (m89-verified), col (n) = l&15
    f32x4 cn4[4];
    #pragma unroll
    for (int i = 0; i < 4; i++)
        cn4[i] = *(const f32x4*)(cn + kbase + wk + i * 16 + l4 * 4);

    #pragma unroll
    for (int j = 0; j < 4; j++) {
        float bv = 3.4e38f; int bi = 0;
        #pragma unroll
        for (int i = 0; i < 4; i++)
            #pragma unroll
            for (int r = 0; r < 4; r++) {
                float s = cn4[i][r] + acc[i][j][r];
                if (s < bv) { bv = s; bi = i * 16 + l4 * 4 + r; }   // ascending scan -> first-min
            }
        // cross-lane reduce over the 4 lane-groups holding this column
        #pragma unroll
        for (int m = 16; m < 64; m <<= 1) {
            float ov = __shfl_xor(bv, m, 64);
            int oi = __shfl_xor(bi, m, 64);
            if (ov < bv || (ov == bv && oi < bi)) { bv = ov; bi = oi; }
        }
        if (lane < 16) {
            u32 u = __float_as_uint(bv);
            u = (u & 0x80000000u) ? ~u : (u | 0x80000000u);
            u64 key = ((u64)u << 32) | (u32)(kbase + wk + bi);
            atomicMin(&packed[nbase + wn + j * 16 + lane], key);
        }
    }
}

// ---------------- gather + losses + histograms ----------------
__global__ void gather_k(const float* __restrict__ z, const float* __restrict__ cb,
                         const u64* __restrict__ packed,
                         float* __restrict__ out_q, float* __restrict__ out_idx,
                         float* __restrict__ out_vq, float* __restrict__ usage,
                         float* __restrict__ embed) {
    int t = threadIdx.x;
    int lane = t & 63, grp = t >> 6;
    int n = blockIdx.x * 64 + lane;
    int idx = (int)(u32)(packed[n] & 0xffffffffULL);
    int b = n >> 10, hw = n & 1023;
    if (grp == 0) {
        out_idx[n] = (float)idx;
        atomicAdd(usage + idx, 1.0f);
    }
    const float* cbrow = cb + (size_t)idx * C_DIM;
    float local = 0.f;
    for (int cc = 0; cc < 64; cc++) {
        int c = grp * 64 + cc;
        size_t zoff = (((size_t)(b * C_DIM + c)) << 10) + hw;
        float zv = z[zoff];
        float q  = cbrow[c];
        out_q[zoff] = q;
        float d = q - zv;
        local += d * d;
        atomicAdd(embed + (size_t)idx * C_DIM + c, zv);
    }
    #pragma unroll
    for (int off = 32; off; off >>= 1) local += __shfl_down(local, off, 64);
    __shared__ float part[4];
    if (lane == 0) part[grp] = local;
    __syncthreads();
    if (t == 0) {
        float s = part[0] + part[1] + part[2] + part[3];
        atomicAdd(out_vq, s * (1.0f / 8388608.0f));
    }
}

// ---------------- perplexity / active codes ----------------
__global__ void metrics_k(const float* __restrict__ usage, float* __restrict__ perp,
                          float* __restrict__ act) {
    __shared__ float sh[256];
    int t = threadIdx.x;
    float s = 0.f;
    for (int i = t; i < K_CB; i += 256) s += usage[i];
    sh[t] = s; __syncthreads();
    for (int off = 128; off; off >>= 1) { if (t < off) sh[t] += sh[t + off]; __syncthreads(); }
    float S = sh[0] > 1.0f ? sh[0] : 1.0f;
    __syncthreads();
    float pl = 0.f, a = 0.f;
    for (int i = t; i < K_CB; i += 256) {
        float u = usage[i];
        float p = u / S;
        float pm = p > 1e-10f ? p : 1e-10f;
        pl += p * logf(pm);
        a += (u > 0.f) ? 1.f : 0.f;
    }
    sh[t] = pl; __syncthreads();
    for (int off = 128; off; off >>= 1) { if (t < off) sh[t] += sh[t + off]; __syncthreads(); }
    if (t == 0) *perp = expf(-sh[0]);
    __syncthreads();
    sh[t] = a; __syncthreads();
    for (int off = 128; off; off >>= 1) { if (t < off) sh[t] += sh[t + off]; __syncthreads(); }
    if (t == 0) *act = sh[0];
}

extern "C" void kernel_launch(void* const* d_in, const int* in_sizes, int n_in,
                              void* d_out, int out_size, void* d_ws, size_t ws_size,
                              hipStream_t stream) {
    const float* z  = (const float*)d_in[0];
    const float* cb = (const float*)d_in[1];
    float* out = (float*)d_out;
    char* ws = (char*)d_ws;

    u16* cbh = (u16*)(ws + WS_CBH);
    u16* cbl = (u16*)(ws + WS_CBL);
    float* cn = (float*)(ws + WS_CN);
    u64* packed = (u64*)(ws + WS_PACKED);

    float* out_q     = out + OFF_Q;
    float* out_idx   = out + OFF_IDX;
    float* out_vq    = out + OFF_VQ;
    float* out_perp  = out + OFF_PERP;
    float* out_act   = out + OFF_ACT;
    float* out_usage = out + OFF_USAGE;
    float* out_embed = out + OFF_EMBED;

    // zh/zl scratch lives in the out_q region (33.55 MB, exact fit);
    // gather_k rewrites out_q with final values after the GEMM.
    u16* zzh = (u16*)out_q;
    u16* zzl = zzh + (size_t)N_VEC * C_DIM;

    hipMemsetAsync(out_vq, 0, (size_t)(1 + 1 + 1 + K_CB + K_CB * C_DIM) * sizeof(float), stream);
    hipMemsetAsync(packed, 0xFF, (size_t)N_VEC * 8, stream);

    split_cb<<<K_CB * C_DIM / 1024, 256, 0, stream>>>(cb, cbh, cbl);
    cnorm_k<<<K_CB, 64, 0, stream>>>((const float4*)cb, cn);
    split_z<<<dim3(32, 8, 32), dim3(32, 8), 0, stream>>>(z, zzh, zzl);
    gemm_mfma<<<dim3(K_CB / 128, N_VEC / 128), 256, 0, stream>>>(cbh, cbl, zzh, zzl, cn, packed);
    gather_k<<<N_VEC / 64, 256, 0, stream>>>(z, cb, packed, out_q, out_idx, out_vq,
                                             out_usage, out_embed);
    metrics_k<<<1, 256, 0, stream>>>(out_usage, out_perp, out_act);
}

// Round 15
// 620.456 us; speedup vs baseline: 7.2591x; 1.5792x over previous
//
#include <hip/hip_runtime.h>

// Problem constants
#define N_VEC 32768   // B*H*W
#define K_CB  8192
#define C_DIM 256

// out layout (floats)
#define OFF_Q     0                      // 8388608
#define OFF_IDX   8388608                // 32768
#define OFF_VQ    8421376                // 1
#define OFF_PERP  8421377                // 1
#define OFF_ACT   8421378                // 1
#define OFF_USAGE 8421379                // 8192
#define OFF_EMBED 8429571                // 2097152

// ws layout (bytes)
#define WS_CBH    0                      // 8192*256*2 = 4194304
#define WS_CBL    4194304                // 4194304
#define WS_CN     8388608                // 8192*4 = 32768
#define WS_PACKED 8421376                // 32768*8 = 262144

typedef unsigned long long u64;
typedef unsigned short u16;
typedef unsigned int u32;
typedef float f32x4 __attribute__((ext_vector_type(4)));
typedef short s16x8 __attribute__((ext_vector_type(8)));

__device__ __forceinline__ u16 rne_bf16(float x) {
    u32 u = __float_as_uint(x);
    return (u16)((u + 0x7fffu + ((u >> 16) & 1u)) >> 16);   // RNE; bf16 = top half of fp32
}
__device__ __forceinline__ float bf16f(u16 h) { return __uint_as_float(((u32)h) << 16); }

// ---------------- codebook split: cbh/cbl = bf16 split of (-2 * cb), [K][C] ----------------
__global__ void split_cb(const float* __restrict__ cb, u16* __restrict__ cbh,
                         u16* __restrict__ cbl) {
    int i = (blockIdx.x * 256 + threadIdx.x) * 4;
    float4 v = *(const float4*)(cb + i);
    ushort4 h, l;
    { float a = -2.0f * v.x; h.x = rne_bf16(a); l.x = rne_bf16(a - bf16f(h.x)); }
    { float a = -2.0f * v.y; h.y = rne_bf16(a); l.y = rne_bf16(a - bf16f(h.y)); }
    { float a = -2.0f * v.z; h.z = rne_bf16(a); l.z = rne_bf16(a - bf16f(h.z)); }
    { float a = -2.0f * v.w; h.w = rne_bf16(a); l.w = rne_bf16(a - bf16f(h.w)); }
    *(ushort4*)(cbh + i) = h;
    *(ushort4*)(cbl + i) = l;
}

// ---------------- codebook norms (fp32, unscaled cb) ----------------
__global__ void cnorm_k(const float4* __restrict__ cb4, float* __restrict__ cn) {
    int k = blockIdx.x;
    int l = threadIdx.x;                      // 64 lanes = 1 wave
    float4 v = cb4[(size_t)k * 64 + l];
    float s = v.x * v.x + v.y * v.y + v.z * v.z + v.w * v.w;
    #pragma unroll
    for (int off = 32; off; off >>= 1) s += __shfl_down(s, off, 64);
    if (l == 0) cn[k] = s;
}

// ---------------- z transpose + bf16 split: zh/zl [N][C] (stored in out_q scratch) ----------------
// r12-proven version (r13's "vectorized" rewrite transposed the tile indices -- reverted).
__global__ void split_z(const float* __restrict__ z, u16* __restrict__ zh,
                        u16* __restrict__ zl) {
    __shared__ float tile[32][33];
    int hw0 = blockIdx.x * 32, c0 = blockIdx.y * 32, b = blockIdx.z;
    int tx = threadIdx.x, ty = threadIdx.y;   // (32, 8)
    #pragma unroll
    for (int i = 0; i < 32; i += 8)
        tile[ty + i][tx] = z[(size_t)b * 262144 + (size_t)(c0 + ty + i) * 1024 + hw0 + tx];
    __syncthreads();
    #pragma unroll
    for (int i = 0; i < 32; i += 8) {
        float v = tile[tx][ty + i];           // (c = c0+tx, hw = hw0+ty+i)
        int n = b * 1024 + hw0 + ty + i;
        u16 h = rne_bf16(v);
        u16 lo = rne_bf16(v - bf16f(h));
        zh[(size_t)n * 256 + c0 + tx] = h;
        zl[(size_t)n * 256 + c0 + tx] = lo;
    }
}

// ---------------- MFMA GEMM + argmin ----------------
// grid (64 k-tiles, 256 n-tiles), block 256 = 4 waves (2k x 2n), wave tile 64k x 64n.
// score(k,n) = cn[k] + sum_c (-2c)[k][c] * v[n][c], 4 bf16 term-GEMMs into one fp32 acc.
// LDS tiles XOR-swizzled: 16B chunk (row, cb) stored at (row, cb ^ (row&3)) -> conflict-free
// ds_read_b128 fragment loads (was 8-way: 3.36e7 SQ_LDS_BANK_CONFLICT in r12).
__launch_bounds__(256, 2)
__global__ void gemm_mfma(const u16* __restrict__ cbh, const u16* __restrict__ cbl,
                          const u16* __restrict__ zh, const u16* __restrict__ zl,
                          const float* __restrict__ cn, u64* __restrict__ packed) {
    __shared__ __align__(16) u16 Ah[128 * 32], Al[128 * 32], Bh[128 * 32], Bl[128 * 32];
    const int kbase = blockIdx.x * 128, nbase = blockIdx.y * 128;
    const int t = threadIdx.x, lane = t & 63, w = t >> 6;
    const int wk = (w >> 1) * 64, wn = (w & 1) * 64;
    const int l15 = lane & 15, l4 = lane >> 4;
    const int sx = l15 & 3;                    // read-side swizzle key (row&3 == l15&3)

    f32x4 acc[4][4];
    const f32x4 zero4 = {0.f, 0.f, 0.f, 0.f};
    #pragma unroll
    for (int i = 0; i < 4; i++)
        #pragma unroll
        for (int j = 0; j < 4; j++) acc[i][j] = zero4;

    // staging chunk geometry: chunk f (0..511) = 16B: row f>>2, colblk f&3
    const int f0 = t, f1 = t + 256;
    const int ar0 = f0 >> 2, ac0 = (f0 & 3) * 8;
    const int ar1 = f1 >> 2, ac1 = (f1 & 3) * 8;
    // swizzled LDS u16 offsets for the two staged chunks
    const int sw0 = ar0 * 32 + (((f0 & 3) ^ (ar0 & 3)) * 8);
    const int sw1 = ar1 * 32 + (((f1 & 3) ^ (ar1 & 3)) * 8);

    const u16* gA0 = cbh + (size_t)(kbase + ar0) * 256 + ac0;
    const u16* gA1 = cbh + (size_t)(kbase + ar1) * 256 + ac1;
    const u16* gAl0 = cbl + (size_t)(kbase + ar0) * 256 + ac0;
    const u16* gAl1 = cbl + (size_t)(kbase + ar1) * 256 + ac1;
    const u16* gB0 = zh + (size_t)(nbase + ar0) * 256 + ac0;
    const u16* gB1 = zh + (size_t)(nbase + ar1) * 256 + ac1;
    const u16* gBl0 = zl + (size_t)(nbase + ar0) * 256 + ac0;
    const u16* gBl1 = zl + (size_t)(nbase + ar1) * 256 + ac1;

    // prologue loads (cs = 0)
    uint4 rA0 = *(const uint4*)(gA0);
    uint4 rA1 = *(const uint4*)(gA1);
    uint4 rAl0 = *(const uint4*)(gAl0);
    uint4 rAl1 = *(const uint4*)(gAl1);
    uint4 rB0 = *(const uint4*)(gB0);
    uint4 rB1 = *(const uint4*)(gB1);
    uint4 rBl0 = *(const uint4*)(gBl0);
    uint4 rBl1 = *(const uint4*)(gBl1);

    for (int cs = 0; cs < 8; ++cs) {
        __syncthreads();                       // all waves done reading previous LDS tile
        *(uint4*)(Ah + sw0) = rA0;  *(uint4*)(Ah + sw1) = rA1;
        *(uint4*)(Al + sw0) = rAl0; *(uint4*)(Al + sw1) = rAl1;
        *(uint4*)(Bh + sw0) = rB0;  *(uint4*)(Bh + sw1) = rB1;
        *(uint4*)(Bl + sw0) = rBl0; *(uint4*)(Bl + sw1) = rBl1;
        __syncthreads();

        // fragment loads (swizzled): A rows wk+i*16+l15, B rows wn+i*16+l15, chunk l4^sx
        s16x8 fah[4], fal[4], fbh[4], fbl[4];
        #pragma unroll
        for (int i = 0; i < 4; i++) {
            int ao = (wk + i * 16 + l15) * 32 + ((l4 ^ sx) * 8);
            int bo = (wn + i * 16 + l15) * 32 + ((l4 ^ sx) * 8);
            fah[i] = *(const s16x8*)(Ah + ao);
            fal[i] = *(const s16x8*)(Al + ao);
            fbh[i] = *(const s16x8*)(Bh + bo);
            fbl[i] = *(const s16x8*)(Bl + bo);
        }

        // prefetch next K-chunk while MFMAs run
        if (cs < 7) {
            int c0n = (cs + 1) * 32;
            rA0 = *(const uint4*)(gA0 + c0n);  rA1 = *(const uint4*)(gA1 + c0n);
            rAl0 = *(const uint4*)(gAl0 + c0n); rAl1 = *(const uint4*)(gAl1 + c0n);
            rB0 = *(const uint4*)(gB0 + c0n);  rB1 = *(const uint4*)(gB1 + c0n);
            rBl0 = *(const uint4*)(gBl0 + c0n); rBl1 = *(const uint4*)(gBl1 + c0n);
        }

        #pragma unroll
        for (int i = 0; i < 4; i++)
            #pragma unroll
            for (int j = 0; j < 4; j++) {
                acc[i][j] = __builtin_amdgcn_mfma_f32_16x16x32_bf16(fah[i], fbh[j], acc[i][j], 0, 0, 0);
                acc[i][j] = __builtin_amdgcn_mfma_f32_16x16x32_bf16(fah[i], fbl[j], acc[i][j], 0, 0, 0);
                acc[i][j] = __builtin_amdgcn_mfma_f32_16x16x32_bf16(fal[i], fbh[j], acc[i][j], 0, 0, 0);
                acc[i][j] = __builtin_amdgcn_mfma_f32_16x16x32_bf16(fal[i], fbl[j], acc[i][j], 0, 0, 0);
            }
    }

    // epilogue: D row (code) = (l>>4)*4 + reg (m89-verified), col (n) = l&15
    f32x4 cn4[4];
    #pragma unroll
    for (int i = 0; i < 4; i++)
        cn4[i] = *(const f32x4*)(cn + kbase + wk + i * 16 + l4 * 4);

    #pragma unroll
    for (int j = 0; j < 4; j++) {
        float bv = 3.4e38f; int bi = 0;
        #pragma unroll
        for (int i = 0; i < 4; i++)
            #pragma unroll
            for (int r = 0; r < 4; r++) {
                float s = cn4[i][r] + acc[i][j][r];
                if (s < bv) { bv = s; bi = i * 16 + l4 * 4 + r; }   // ascending scan -> first-min
            }
        // cross-lane reduce over the 4 lane-groups holding this column
        #pragma unroll
        for (int m = 16; m < 64; m <<= 1) {
            float ov = __shfl_xor(bv, m, 64);
            int oi = __shfl_xor(bi, m, 64);
            if (ov < bv || (ov == bv && oi < bi)) { bv = ov; bi = oi; }
        }
        if (lane < 16) {
            u32 u = __float_as_uint(bv);
            u = (u & 0x80000000u) ? ~u : (u | 0x80000000u);
            u64 key = ((u64)u << 32) | (u32)(kbase + wk + bi);
            atomicMin(&packed[nbase + wn + j * 16 + lane], key);
        }
    }
}

// ---------------- gather + losses + histograms ----------------
// grid 512 (64 n each), block 256 (4 waves). z block staged in LDS; embed atomics
// issued wave-per-n with lanes over c -> coalesced (131K atomic instrs vs 8.4M scattered).
__global__ void gather_k(const float* __restrict__ z, const float* __restrict__ cb,
                         const u64* __restrict__ packed,
                         float* __restrict__ out_q, float* __restrict__ out_idx,
                         float* __restrict__ out_vq, float* __restrict__ usage,
                         float* __restrict__ embed) {
    __shared__ float zb[64][257];
    __shared__ int idxs[64];
    __shared__ float part[4];
    int t = threadIdx.x;
    int lane = t & 63, grp = t >> 6;
    int n0 = blockIdx.x * 64;
    int b = n0 >> 10, hw0 = n0 & 1023;        // 64 | 1024 -> single b per block

    // stage z block [64 n][256 c]: lanes = hw (coalesced 256B), grp covers c quarters
    for (int cc = 0; cc < 64; cc++) {
        int c = grp * 64 + cc;
        zb[lane][c] = z[(((size_t)(b * C_DIM + c)) << 10) + hw0 + lane];
    }
    if (t < 64) idxs[t] = (int)(u32)(packed[n0 + t] & 0xffffffffULL);
    __syncthreads();

    int idx = idxs[lane];
    if (grp == 0) {
        out_idx[n0 + lane] = (float)idx;
        atomicAdd(usage + idx, 1.0f);
    }
    const float* cbrow = cb + (size_t)idx * C_DIM;
    float local = 0.f;
    for (int cc = 0; cc < 64; cc++) {
        int c = grp * 64 + cc;
        float zv = zb[lane][c];
        float q  = cbrow[c];
        out_q[(((size_t)(b * C_DIM + c)) << 10) + hw0 + lane] = q;
        float d = q - zv;
        local += d * d;
    }
    #pragma unroll
    for (int off = 32; off; off >>= 1) local += __shfl_down(local, off, 64);
    if (lane == 0) part[grp] = local;
    __syncthreads();
    if (t == 0) {
        float s = part[0] + part[1] + part[2] + part[3];
        atomicAdd(out_vq, s * (1.0f / 8388608.0f));
    }

    // phase 2: embed scatter-add, wave grp handles 16 n, lanes over c (coalesced)
    for (int i = 0; i < 16; i++) {
        int no = grp * 16 + i;
        float* erow = embed + (size_t)idxs[no] * C_DIM;
        #pragma unroll
        for (int j = 0; j < 4; j++) {
            int c = j * 64 + lane;
            atomicAdd(erow + c, zb[no][c]);
        }
    }
}

// ---------------- perplexity / active codes ----------------
__global__ void metrics_k(const float* __restrict__ usage, float* __restrict__ perp,
                          float* __restrict__ act) {
    __shared__ float sh[256];
    int t = threadIdx.x;
    float s = 0.f;
    for (int i = t; i < K_CB; i += 256) s += usage[i];
    sh[t] = s; __syncthreads();
    for (int off = 128; off; off >>= 1) { if (t < off) sh[t] += sh[t + off]; __syncthreads(); }
    float S = sh[0] > 1.0f ? sh[0] : 1.0f;
    __syncthreads();
    float pl = 0.f, a = 0.f;
    for (int i = t; i < K_CB; i += 256) {
        float u = usage[i];
        float p = u / S;
        float pm = p > 1e-10f ? p : 1e-10f;
        pl += p * logf(pm);
        a += (u > 0.f) ? 1.f : 0.f;
    }
    sh[t] = pl; __syncthreads();
    for (int off = 128; off; off >>= 1) { if (t < off) sh[t] += sh[t + off]; __syncthreads(); }
    if (t == 0) *perp = expf(-sh[0]);
    __syncthreads();
    sh[t] = a; __syncthreads();
    for (int off = 128; off; off >>= 1) { if (t < off) sh[t] += sh[t + off]; __syncthreads(); }
    if (t == 0) *act = sh[0];
}

extern "C" void kernel_launch(void* const* d_in, const int* in_sizes, int n_in,
                              void* d_out, int out_size, void* d_ws, size_t ws_size,
                              hipStream_t stream) {
    const float* z  = (const float*)d_in[0];
    const float* cb = (const float*)d_in[1];
    float* out = (float*)d_out;
    char* ws = (char*)d_ws;

    u16* cbh = (u16*)(ws + WS_CBH);
    u16* cbl = (u16*)(ws + WS_CBL);
    float* cn = (float*)(ws + WS_CN);
    u64* packed = (u64*)(ws + WS_PACKED);

    float* out_q     = out + OFF_Q;
    float* out_idx   = out + OFF_IDX;
    float* out_vq    = out + OFF_VQ;
    float* out_perp  = out + OFF_PERP;
    float* out_act   = out + OFF_ACT;
    float* out_usage = out + OFF_USAGE;
    float* out_embed = out + OFF_EMBED;

    // zh/zl scratch lives in the out_q region (33.55 MB, exact fit);
    // gather_k rewrites out_q with final values after the GEMM.
    u16* zzh = (u16*)out_q;
    u16* zzl = zzh + (size_t)N_VEC * C_DIM;

    hipMemsetAsync(out_vq, 0, (size_t)(1 + 1 + 1 + K_CB + K_CB * C_DIM) * sizeof(float), stream);
    hipMemsetAsync(packed, 0xFF, (size_t)N_VEC * 8, stream);

    split_cb<<<K_CB * C_DIM / 1024, 256, 0, stream>>>(cb, cbh, cbl);
    cnorm_k<<<K_CB, 64, 0, stream>>>((const float4*)cb, cn);
    split_z<<<dim3(32, 8, 32), dim3(32, 8), 0, stream>>>(z, zzh, zzl);
    gemm_mfma<<<dim3(K_CB / 128, N_VEC / 128), 256, 0, stream>>>(cbh, cbl, zzh, zzl, cn, packed);
    gather_k<<<N_VEC / 64, 256, 0, stream>>>(z, cb, packed, out_q, out_idx, out_vq,
                                             out_usage, out_embed);
    metrics_k<<<1, 256, 0, stream>>>(out_usage, out_perp, out_act);
}